// Round 9
// baseline (487.033 us; speedup 1.0000x reference)
//
#include <hip/hip_runtime.h>

#define DIM   64
#define NEMB  1024
#define HW    4096      // 64*64
#define NPIX  131072    // 32*64*64
#define NOUT  8388608   // 32*64*64*64
#define TILE  128       // pixels per block (39KB LDS -> 4 blocks/CU)
#define JC    16        // codes per register tile
#define CPS   256       // codes per wave (4 waves cover 1024)

// ---------------------------------------------------------------------------
// prep: cn[j] = ||e_j||^2, numpy axis-0 semantics (sequential adds over the
// outer axis — numpy reduces axis 0 of [64,1024] as 64 row-adds).
// ---------------------------------------------------------------------------
__global__ __launch_bounds__(256) void prep_kernel(const float* __restrict__ embed,
                                                   float* __restrict__ cn) {
    const int j = blockIdx.x * 256 + threadIdx.x;
    if (j >= NEMB) return;
    float v = embed[j];
    float s = __fmul_rn(v, v);
#pragma unroll
    for (int d = 1; d < DIM; ++d) {
        v = embed[d * NEMB + j];
        s = __fadd_rn(s, __fmul_rn(v, v));
    }
    cn[j] = s;
}

// ---------------------------------------------------------------------------
// fused VQ kernel. x staged in LDS (R2-R5: regalloc never keeps x[64]
// resident). R7 lesson: e-rows via s_load cap VALUBusy at 66% independent of
// occupancy (scalar-cache serialization + ds/smem lgkmcnt mixing forcing
// lgkmcnt(0) drains). Fix: launder the uniform e-row pointer into a VGPR so
// the loads take the VECTOR path (global_load_dwordx4 broadcast, vmcnt) —
// decoupled from the ds_read lgkmcnt stream, deep miss queue, compiler can
// software-pipeline across d-chunks.
// Distance arithmetic identical to the R0-passing kernel; packed-u64 min
// merge = exact first-occurrence argmin.
// ---------------------------------------------------------------------------
__global__ __launch_bounds__(256)
__attribute__((amdgpu_waves_per_eu(4, 4)))
void vq_kernel(const float* __restrict__ X,
               const float* __restrict__ embed,
               const float* __restrict__ cn,
               float* __restrict__ OUT,
               float* __restrict__ loss) {
    __shared__ float x_lds[DIM][TILE];            // 32 KB
    __shared__ float ff_lds[TILE];                // 512 B
    __shared__ unsigned long long sm[4 * TILE];   // 4 KB
    __shared__ int   idx_lds[TILE];               // 512 B
    __shared__ float sred[256];                   // 1 KB

    const int tid  = threadIdx.x;
    const int l    = tid & 63;
    const int w    = tid >> 6;
    const int pix0 = blockIdx.x * TILE;
    const int b    = pix0 >> 12;        // 128 | 4096 -> same image per block
    const int p0   = pix0 & 4095;

    // ---- stage: threads 0..127 own pixel tid; load 64 d-values (coalesced
    //      across lanes per d), write LDS, compute ||f||^2 with the numpy
    //      pairwise-8 pattern from the register copies (bitwise == R6/R7).
    if (tid < TILE) {
        const float* xb = X + (size_t)b * (DIM * HW) + p0 + tid;
        float rr[8];
#pragma unroll
        for (int i = 0; i < 8; ++i) {
            const float v = xb[(size_t)i * HW];
            x_lds[i][tid] = v;
            rr[i] = __fmul_rn(v, v);
        }
#pragma unroll
        for (int i = 8; i < DIM; i += 8)
#pragma unroll
            for (int q = 0; q < 8; ++q) {
                const float v = xb[(size_t)(i + q) * HW];
                x_lds[i + q][tid] = v;
                rr[q] = __fadd_rn(rr[q], __fmul_rn(v, v));
            }
        ff_lds[tid] = __fadd_rn(
            __fadd_rn(__fadd_rn(rr[0], rr[1]), __fadd_rn(rr[2], rr[3])),
            __fadd_rn(__fadd_rn(rr[4], rr[5]), __fadd_rn(rr[6], rr[7])));
    }
    __syncthreads();

    // ---- scan: wave w covers codes [w*CPS, w*CPS+CPS) for pixels 2l, 2l+1
    const int jbase = w * CPS;
    const float ffa = ff_lds[2 * l];
    const float ffb = ff_lds[2 * l + 1];

    float minva = __builtin_inff(), minvb = __builtin_inff();
    int   minia = 0, minib = 0;

#pragma unroll 1
    for (int g = 0; g < CPS / JC; ++g) {
        const int j0 = jbase + g * JC;
        float acca[JC], accb[JC];
#pragma unroll
        for (int c = 0; c < JC; ++c) { acca[c] = 0.f; accb[c] = 0.f; }

#pragma unroll 4
        for (int d = 0; d < DIM; ++d) {
            // launder the (block-uniform) row address into a VGPR: forces the
            // VECTOR load path (global_load_dwordx4 broadcast, vmcnt) instead
            // of s_load (lgkmcnt) -- R7's occupancy-independent 66% cap.
            const float* erow_d = embed + (size_t)d * NEMB + j0;
            asm("" : "+v"(erow_d));
            const float4 e0 = reinterpret_cast<const float4*>(erow_d)[0];
            const float4 e1 = reinterpret_cast<const float4*>(erow_d)[1];
            const float4 e2 = reinterpret_cast<const float4*>(erow_d)[2];
            const float4 e3 = reinterpret_cast<const float4*>(erow_d)[3];
            const float2 x2 = *reinterpret_cast<const float2*>(&x_lds[d][2 * l]);
            const float ev[JC] = {e0.x, e0.y, e0.z, e0.w,
                                  e1.x, e1.y, e1.z, e1.w,
                                  e2.x, e2.y, e2.z, e2.w,
                                  e3.x, e3.y, e3.z, e3.w};
#pragma unroll
            for (int c = 0; c < JC; ++c) {
                acca[c] = fmaf(x2.x, ev[c], acca[c]);   // sequential-d chain per
                accb[c] = fmaf(x2.y, ev[c], accb[c]);   // (pix,code) == R0 order
            }
        }
#pragma unroll
        for (int c = 0; c < JC; ++c) {
            const float cnj = cn[j0 + c];
            const float da = __fadd_rn(__fsub_rn(ffa, __fmul_rn(2.f, acca[c])), cnj);
            const float db = __fadd_rn(__fsub_rn(ffb, __fmul_rn(2.f, accb[c])), cnj);
            if (da < minva) { minva = da; minia = j0 + c; }   // strict <
            if (db < minvb) { minvb = db; minib = j0 + c; }
        }
    }

    sm[w * TILE + 2 * l] =
        ((unsigned long long)__float_as_uint(minva) << 32) | (unsigned)minia;
    sm[w * TILE + 2 * l + 1] =
        ((unsigned long long)__float_as_uint(minvb) << 32) | (unsigned)minib;
    __syncthreads();

    // ---- merge 4 waves (dist>0 -> bit order valid; low-32 idx -> exact
    //      ties pick the smaller index = np.argmin first occurrence)
    if (tid < TILE) {
        unsigned long long m = sm[tid];
#pragma unroll
        for (int s = 1; s < 4; ++s) {
            const unsigned long long c2 = sm[s * TILE + tid];
            m = (c2 < m) ? c2 : m;
        }
        idx_lds[tid] = (int)(m & 0xFFFFFFFFull);
    }
    __syncthreads();

    // ---- output + loss: thread t -> pixel t&127, d-half t>>7. x from LDS,
    //      embed gather L2-resident (256 KB), writes coalesced across pix.
    const int pixe = tid & (TILE - 1);
    const int dh   = tid >> 7;            // 0 or 1 -> d in [32dh, 32dh+32)
    const int idx  = idx_lds[pixe];
    float lerr = 0.f;
    float* outb = OUT + (size_t)b * (DIM * HW) + p0 + pixe;
#pragma unroll 8
    for (int k = 0; k < DIM / 2; ++k) {
        const int d = dh * (DIM / 2) + k;
        const float qv = embed[d * NEMB + idx];
        const float xv = x_lds[d][pixe];
        const float df = __fsub_rn(qv, xv);
        outb[(size_t)d * HW] = __fadd_rn(xv, df);
        lerr = fmaf(df, df, lerr);
    }

    sred[tid] = lerr;
    __syncthreads();
#pragma unroll
    for (int s = 128; s > 0; s >>= 1) {
        if (tid < s) sred[tid] += sred[tid + s];
        __syncthreads();
    }
    if (tid == 0)
        atomicAdd(loss, sred[0] * (1.0f / (float)NOUT));
}

extern "C" void kernel_launch(void* const* d_in, const int* in_sizes, int n_in,
                              void* d_out, int out_size, void* d_ws, size_t ws_size,
                              hipStream_t stream) {
    const float* X = (const float*)d_in[0];
    const float* E = (const float*)d_in[1];
    float* OUT  = (float*)d_out;
    float* loss = OUT + NOUT;
    float* cn   = (float*)d_ws;    // 1024 floats

    hipMemsetAsync(loss, 0, sizeof(float), stream);
    prep_kernel<<<NEMB / 256, 256, 0, stream>>>(E, cn);
    vq_kernel<<<NPIX / TILE, 256, 0, stream>>>(X, E, cn, OUT, loss);
}

// Round 10
// 142.099 us; speedup vs baseline: 3.4274x; 3.4274x over previous
//
#include <hip/hip_runtime.h>

#define DIM    64
#define NEMB   1024
#define HW     4096      // 64*64
#define NPIX   131072    // 32*64*64
#define NOUT   8388608   // 32*64*64*64
#define PIXBLK 128       // pixels per block
#define NTILE  64        // 1024/16 code tiles
#define CAP    2048      // worklist capacity (expected ~190 entries)
#define MARGIN 0.5f      // >> 2*eps(screen) ~ 0.02

using short8 = __attribute__((ext_vector_type(8))) short;
using f32x4  = __attribute__((ext_vector_type(4))) float;

#define MFMA(A, B, C) __builtin_amdgcn_mfma_f32_16x16x32_bf16((A), (B), (C), 0, 0, 0)

__device__ __forceinline__ unsigned short bf16_rne(float f) {
    unsigned u = __float_as_uint(f);
    return (unsigned short)((u + 0x7fffu + ((u >> 16) & 1u)) >> 16);
}
__device__ __forceinline__ float bf16_val(unsigned short h) {
    return __uint_as_float((unsigned)h << 16);
}
__device__ __forceinline__ void umin64(unsigned long long* p, unsigned long long v) {
    unsigned long long old = *p;
    while (v < old) {
        unsigned long long a = atomicCAS(p, old, v);
        if (a == old) break;
        old = a;
    }
}

// ---------------------------------------------------------------------------
// prep1: cn[j] = ||e_j||^2 (numpy axis-0 order: sequential adds of rounded
// muls) and eT[j][d] = embed[d][j] for the exact rescore path.
// ---------------------------------------------------------------------------
__global__ __launch_bounds__(256) void prep1(const float* __restrict__ embed,
                                             float* __restrict__ cn,
                                             float* __restrict__ eT) {
    const int j = blockIdx.x * 256 + threadIdx.x;
    if (j >= NEMB) return;
    float v = embed[j];
    eT[j * DIM] = v;
    float s = __fmul_rn(v, v);
#pragma unroll
    for (int d = 1; d < DIM; ++d) {
        v = embed[d * NEMB + j];
        eT[j * DIM + d] = v;
        s = __fadd_rn(s, __fmul_rn(v, v));
    }
    cn[j] = s;
}

// ---------------------------------------------------------------------------
// prep2: split -2*embed into bf16 hi/lo, stored in MFMA A-fragment order:
// A[row=code][k=d] for tile ct, K-chunk kc: lane l holds row=l&15,
// k = (l>>4)*8 + i.  flat = ((ct*2+kc)*64 + lane)*8 + i.
// ---------------------------------------------------------------------------
__global__ __launch_bounds__(256) void prep2(const float* __restrict__ embed,
                                             unsigned short* __restrict__ ehi,
                                             unsigned short* __restrict__ elo) {
    const int gid = blockIdx.x * 256 + threadIdx.x;   // 64*1024 elements
    const int d = gid >> 10;
    const int j = gid & 1023;
    const float es = -2.0f * embed[d * NEMB + j];
    const unsigned short h = bf16_rne(es);
    const unsigned short lo = bf16_rne(es - bf16_val(h));
    const int ct = j >> 4, r = j & 15;
    const int kc = d >> 5, g = (d >> 3) & 3, i = d & 7;
    const int idx = ((ct * 2 + kc) * 64 + (g * 16 + r)) * 8 + i;
    ehi[idx] = h;
    elo[idx] = lo;
}

// ---------------------------------------------------------------------------
// prep3: cn in C-fragment order: lane l, reg q -> code ct*16 + (l>>4)*4 + q.
// ---------------------------------------------------------------------------
__global__ __launch_bounds__(256) void prep3(const float* __restrict__ cn,
                                             float* __restrict__ cnfrag) {
    const int t = blockIdx.x * 256 + threadIdx.x;     // 64*64*4
    const int q = t & 3, l = (t >> 2) & 63, ct = t >> 8;
    cnfrag[t] = cn[ct * 16 + (l >> 4) * 4 + q];
}

// ---------------------------------------------------------------------------
// vq: per block of 128 pixels:
//  1. stage x into LDS + ff (pairwise-8, bitwise == R7)
//  2. MFMA screen: wave w owns 2 subtiles of 16 pixels; D[16 codes x 16 pix]
//     = (-2e)*x + cn via split-bf16 (ehi*xh + elo*xh + ehi*xl), fp32 acc.
//     Per-tile per-pixel min -> tm_lds.
//  3. candidates: tiles with tm <= min + MARGIN -> LDS worklist
//  4. exact rescore of candidate tiles with the R0-proven fp32 chain,
//     packed-u64 min (ties -> smaller index = np.argmin)
//  5. output q = x + (q - x), loss (same as R7)
// ---------------------------------------------------------------------------
__global__ __launch_bounds__(256)
__attribute__((amdgpu_waves_per_eu(2, 2)))
void vq_kernel(const float* __restrict__ X,
               const float* __restrict__ embed,
               const float* __restrict__ cn,
               const float* __restrict__ eT,
               const float* __restrict__ cnfrag,
               const unsigned short* __restrict__ ehi,
               const unsigned short* __restrict__ elo,
               float* __restrict__ OUT,
               float* __restrict__ loss) {
    __shared__ float x_lds[DIM][PIXBLK];            // 32 KB
    __shared__ float ff_lds[PIXBLK];                // 512 B
    __shared__ float tm_lds[PIXBLK * 65];           // 33.3 KB (padded rows)
    __shared__ unsigned long long best_lds[PIXBLK]; // 1 KB
    __shared__ unsigned wl[CAP];                    // 8 KB
    __shared__ int wl_cnt, wl_ovf;
    __shared__ float sred[256];                     // 1 KB

    const int tid  = threadIdx.x;
    const int l    = tid & 63;
    const int w    = tid >> 6;
    const int pix0 = blockIdx.x * PIXBLK;
    const int b    = pix0 >> 12;
    const int p0   = pix0 & 4095;

    // ---- 1. stage (threads 0..127), bitwise identical to R7
    if (tid < PIXBLK) {
        const float* xb = X + (size_t)b * (DIM * HW) + p0 + tid;
        float rr[8];
#pragma unroll
        for (int i = 0; i < 8; ++i) {
            const float v = xb[(size_t)i * HW];
            x_lds[i][tid] = v;
            rr[i] = __fmul_rn(v, v);
        }
#pragma unroll
        for (int i = 8; i < DIM; i += 8)
#pragma unroll
            for (int q = 0; q < 8; ++q) {
                const float v = xb[(size_t)(i + q) * HW];
                x_lds[i + q][tid] = v;
                rr[q] = __fadd_rn(rr[q], __fmul_rn(v, v));
            }
        ff_lds[tid] = __fadd_rn(
            __fadd_rn(__fadd_rn(rr[0], rr[1]), __fadd_rn(rr[2], rr[3])),
            __fadd_rn(__fadd_rn(rr[4], rr[5]), __fadd_rn(rr[6], rr[7])));
        best_lds[tid] = 0xFFFFFFFFFFFFFFFFull;
    }
    if (tid == 0) { wl_cnt = 0; wl_ovf = 0; }
    __syncthreads();

    // ---- 2. B-fragments: x split to bf16 hi/lo, fragment layout
    //      B[k=d][col=pix]: lane l holds k=(l>>4)*8+i, col=l&15.
    const int g  = l >> 4;
    const int lr = l & 15;
    short8 xh0[2], xl0[2], xh1[2], xl1[2];   // [kc] for subtile 0/1
#pragma unroll
    for (int kc = 0; kc < 2; ++kc)
#pragma unroll
        for (int i = 0; i < 8; ++i) {
            const int d = kc * 32 + g * 8 + i;
            {
                const float v = x_lds[d][(w * 2 + 0) * 16 + lr];
                const unsigned short h = bf16_rne(v);
                xh0[kc][i] = (short)h;
                xl0[kc][i] = (short)bf16_rne(v - bf16_val(h));
            }
            {
                const float v = x_lds[d][(w * 2 + 1) * 16 + lr];
                const unsigned short h = bf16_rne(v);
                xh1[kc][i] = (short)h;
                xl1[kc][i] = (short)bf16_rne(v - bf16_val(h));
            }
        }

    // ---- screen loop over 64 code tiles, 1-deep prefetch
    f32x4  cnv = *(const f32x4*)(cnfrag + (0 * 64 + l) * 4);
    short8 eh0 = *(const short8*)(ehi + ((0 * 2 + 0) * 64 + l) * 8);
    short8 eh1 = *(const short8*)(ehi + ((0 * 2 + 1) * 64 + l) * 8);
    short8 el0 = *(const short8*)(elo + ((0 * 2 + 0) * 64 + l) * 8);
    short8 el1 = *(const short8*)(elo + ((0 * 2 + 1) * 64 + l) * 8);

#pragma unroll 1
    for (int ct = 0; ct < NTILE; ++ct) {
        f32x4 cnv_n = cnv;
        short8 eh0n = eh0, eh1n = eh1, el0n = el0, el1n = el1;
        if (ct + 1 < NTILE) {
            const int t2 = (ct + 1) * 2;
            cnv_n = *(const f32x4*)(cnfrag + ((ct + 1) * 64 + l) * 4);
            eh0n = *(const short8*)(ehi + ((t2 + 0) * 64 + l) * 8);
            eh1n = *(const short8*)(ehi + ((t2 + 1) * 64 + l) * 8);
            el0n = *(const short8*)(elo + ((t2 + 0) * 64 + l) * 8);
            el1n = *(const short8*)(elo + ((t2 + 1) * 64 + l) * 8);
        }
        // screen = cn - 2*dot (e pre-scaled by -2): 6 MFMAs per subtile
        f32x4 a0 = cnv, a1 = cnv;
        a0 = MFMA(eh0, xh0[0], a0);  a1 = MFMA(eh0, xh1[0], a1);
        a0 = MFMA(eh1, xh0[1], a0);  a1 = MFMA(eh1, xh1[1], a1);
        a0 = MFMA(el0, xh0[0], a0);  a1 = MFMA(el0, xh1[0], a1);
        a0 = MFMA(el1, xh0[1], a0);  a1 = MFMA(el1, xh1[1], a1);
        a0 = MFMA(eh0, xl0[0], a0);  a1 = MFMA(eh0, xl1[0], a1);
        a0 = MFMA(eh1, xl0[1], a0);  a1 = MFMA(eh1, xl1[1], a1);

        float t0 = fminf(fminf(a0[0], a0[1]), fminf(a0[2], a0[3]));
        float t1 = fminf(fminf(a1[0], a1[1]), fminf(a1[2], a1[3]));
        t0 = fminf(t0, __shfl_xor(t0, 16, 64));
        t0 = fminf(t0, __shfl_xor(t0, 32, 64));
        t1 = fminf(t1, __shfl_xor(t1, 16, 64));
        t1 = fminf(t1, __shfl_xor(t1, 32, 64));
        if (l < 16) {
            tm_lds[((w * 2 + 0) * 16 + l) * 65 + ct] = t0;
            tm_lds[((w * 2 + 1) * 16 + l) * 65 + ct] = t1;
        }
        cnv = cnv_n; eh0 = eh0n; eh1 = eh1n; el0 = el0n; el1 = el1n;
    }
    __syncthreads();

    // ---- 3. enumerate candidate tiles per pixel
    if (tid < PIXBLK) {
        const float* tr = tm_lds + tid * 65;
        float mm = tr[0];
#pragma unroll
        for (int ct = 1; ct < NTILE; ++ct) mm = fminf(mm, tr[ct]);
        const float thr = mm + MARGIN;
        for (int ct = 0; ct < NTILE; ++ct)
            if (tr[ct] <= thr) {
                const int slot = atomicAdd(&wl_cnt, 1);
                if (slot < CAP) wl[slot] = (unsigned)((tid << 6) | ct);
                else wl_ovf = 1;
            }
    }
    __syncthreads();

    // ---- 4. exact rescore of worklist entries (R0-proven fp32 chain)
    const int ec = wl_cnt < CAP ? wl_cnt : CAP;
#pragma unroll 1
    for (int e2 = tid; e2 < ec; e2 += 256) {
        const unsigned ent = wl[e2];
        const int pix = ent >> 6, ct = ent & 63;
        const float ffv = ff_lds[pix];
        unsigned long long bb = 0xFFFFFFFFFFFFFFFFull;
#pragma unroll 1
        for (int c = 0; c < 16; ++c) {
            const int j = ct * 16 + c;
            const float* er = eT + j * DIM;
            float a = 0.f;
#pragma unroll
            for (int d = 0; d < DIM; ++d)
                a = fmaf(x_lds[d][pix], er[d], a);   // sequential-d == R0
            const float dist = __fadd_rn(__fsub_rn(ffv, __fmul_rn(2.f, a)), cn[j]);
            const unsigned long long pk =
                ((unsigned long long)__float_as_uint(dist) << 32) | (unsigned)j;
            bb = pk < bb ? pk : bb;
        }
        umin64(&best_lds[pix], bb);
    }
    __syncthreads();

    if (wl_ovf) {   // overflow fallback: exact scan of all codes (never in practice)
        if (tid < PIXBLK) {
            const float ffv = ff_lds[tid];
            unsigned long long bb = best_lds[tid];
            for (int j = 0; j < NEMB; ++j) {
                const float* er = eT + j * DIM;
                float a = 0.f;
#pragma unroll
                for (int d = 0; d < DIM; ++d)
                    a = fmaf(x_lds[d][tid], er[d], a);
                const float dist = __fadd_rn(__fsub_rn(ffv, __fmul_rn(2.f, a)), cn[j]);
                const unsigned long long pk =
                    ((unsigned long long)__float_as_uint(dist) << 32) | (unsigned)j;
                bb = pk < bb ? pk : bb;
            }
            best_lds[tid] = bb;
        }
        __syncthreads();
    }

    // ---- 5. output + loss (same structure as R7)
    const int pixe = tid & (PIXBLK - 1);
    const int dh   = tid >> 7;
    const int idx  = (int)(best_lds[pixe] & 0xFFFFFFFFull);
    float lerr = 0.f;
    float* outb = OUT + (size_t)b * (DIM * HW) + p0 + pixe;
#pragma unroll 8
    for (int k = 0; k < DIM / 2; ++k) {
        const int d = dh * (DIM / 2) + k;
        const float qv = embed[d * NEMB + idx];
        const float xv = x_lds[d][pixe];
        const float df = __fsub_rn(qv, xv);
        outb[(size_t)d * HW] = __fadd_rn(xv, df);
        lerr = fmaf(df, df, lerr);
    }

    sred[tid] = lerr;
    __syncthreads();
#pragma unroll
    for (int s = 128; s > 0; s >>= 1) {
        if (tid < s) sred[tid] += sred[tid + s];
        __syncthreads();
    }
    if (tid == 0)
        atomicAdd(loss, sred[0] * (1.0f / (float)NOUT));
}

extern "C" void kernel_launch(void* const* d_in, const int* in_sizes, int n_in,
                              void* d_out, int out_size, void* d_ws, size_t ws_size,
                              hipStream_t stream) {
    const float* X = (const float*)d_in[0];
    const float* E = (const float*)d_in[1];
    float* OUT  = (float*)d_out;
    float* loss = OUT + NOUT;

    // ws layout (bytes): cn 4K | eT 256K | cnfrag 64K | ehi 128K | elo 128K
    char* wsb = (char*)d_ws;
    float* cn            = (float*)(wsb);
    float* eT            = (float*)(wsb + 4096);
    float* cnfrag        = (float*)(wsb + 4096 + 262144);
    unsigned short* ehi  = (unsigned short*)(wsb + 4096 + 262144 + 65536);
    unsigned short* elo  = (unsigned short*)(wsb + 4096 + 262144 + 65536 + 131072);

    hipMemsetAsync(loss, 0, sizeof(float), stream);
    prep1<<<NEMB / 256, 256, 0, stream>>>(E, cn, eT);
    prep2<<<(DIM * NEMB) / 256, 256, 0, stream>>>(E, ehi, elo);
    prep3<<<(NTILE * 64 * 4) / 256, 256, 0, stream>>>(cn, cnfrag);
    vq_kernel<<<NPIX / PIXBLK, 256, 0, stream>>>(X, E, cn, eT, cnfrag, ehi, elo,
                                                 OUT, loss);
}